// Round 7
// baseline (649.703 us; speedup 1.0000x reference)
//
#include <hip/hip_runtime.h>

#define GRID 64
#define NVOX (GRID*GRID*GRID)
#define NCLS 20
#define NSEED 512

// ---------------- weight transposes, one launch ----------------
// w1t[(nb*6+ci)*64+oc] = w1[oc][ci][nb];  w2t[(nb*64+ci)*32+oc] = w2[oc][ci][nb]
__global__ void transpose_all(const float* __restrict__ w1, float* __restrict__ w1t,
                              const float* __restrict__ w2, float* __restrict__ w2t) {
    int t = blockIdx.x * 256 + threadIdx.x;
    if (t < 27 * 6 * 64) {
        int oc = t & 63;
        int r  = t >> 6;            // nb*6 + ci
        int nb = r / 6, ci = r % 6;
        w1t[t] = w1[oc * 162 + ci * 27 + nb];
        return;
    }
    t -= 27 * 6 * 64;
    if (t < 27 * 64 * 32) {
        int oc = t & 31;
        int r  = t >> 5;            // nb*64 + ci
        int nb = r >> 6, ci = r & 63;
        w2t[t] = w2[oc * 1728 + ci * 27 + nb];
    }
}

// ------- conv1 (6->64): Zd=8, og=4-of-64, all-tap LDS weights, barrier-free -------
// grid 2048 = 8 zg (XCD) x 16 og x 16 yt; og varies fastest within XCD.
__global__ __launch_bounds__(256, 4) void conv1_kernel(
    const float* __restrict__ feat,   // [6][NVOX]
    const float* __restrict__ w1t,    // [(nb*6+ci)][64]
    const float* __restrict__ b1,
    float* __restrict__ h1p)          // [32][NVOX][2] channel-pair-major
{
    __shared__ float lw[27 * 6 * 4];  // this og's weights, all taps: 2592 B

    int tid = threadIdx.x;
    int B = blockIdx.x;
    int zg = B & 7;
    int k  = B >> 3;                  // 0..255
    int og = k & 15;                  // oc group of 4 (fastest -> L2 sharing)
    int yt = k >> 4;                  // 0..15

    for (int t = tid; t < 27 * 6 * 4; t += 256)
        lw[t] = w1t[(t >> 2) * 64 + og * 4 + (t & 3)];
    __syncthreads();                  // the only barrier

    int x  = tid & 63;
    int y  = yt * 4 + (tid >> 6);     // wave-uniform
    int z0 = zg * 8;

    float acc[8][4];
    #pragma unroll
    for (int r = 0; r < 8; ++r)
        #pragma unroll
        for (int o = 0; o < 4; ++o) acc[r][o] = 0.f;

    int zoffv[10]; float mzv[10];
    #pragma unroll
    for (int rz = 0; rz < 10; ++rz) {
        int gz = z0 - 1 + rz;
        int cz = gz < 0 ? 0 : (gz > 63 ? 63 : gz);
        zoffv[rz] = cz * 4096;
        mzv[rz] = ((unsigned)gz < 64u) ? 1.f : 0.f;
    }

    #pragma unroll 1
    for (int dydx = 0; dydx < 9; ++dydx) {
        int dy = dydx / 3 - 1;
        int dx = dydx % 3 - 1;
        int ny = y + dy;
        if ((unsigned)ny >= 64u) continue;             // wave-uniform zero-pad skip
        int nx = x + dx;
        float mx = ((unsigned)nx < 64u) ? 1.f : 0.f;
        int cx = nx < 0 ? 0 : (nx > 63 ? 63 : nx);
        int rowvox = ny * 64 + cx;

        float cm[10]; int voff[10];
        #pragma unroll
        for (int rz = 0; rz < 10; ++rz) { cm[rz] = mx * mzv[rz]; voff[rz] = zoffv[rz] + rowvox; }

        #pragma unroll 1
        for (int ci = 0; ci < 6; ++ci) {
            const float* plane = feat + (size_t)ci * NVOX;
            float v[10];
            #pragma unroll
            for (int rz = 0; rz < 10; ++rz) v[rz] = plane[voff[rz]] * cm[rz];
            #pragma unroll
            for (int dzi = 0; dzi < 3; ++dzi) {
                const float4 w0 = *reinterpret_cast<const float4*>(
                    &lw[(((dzi * 9 + dydx) * 6) + ci) * 4]);
                #pragma unroll
                for (int r = 0; r < 8; ++r) {
                    float a = v[r + dzi];
                    acc[r][0] = fmaf(a, w0.x, acc[r][0]);
                    acc[r][1] = fmaf(a, w0.y, acc[r][1]);
                    acc[r][2] = fmaf(a, w0.z, acc[r][2]);
                    acc[r][3] = fmaf(a, w0.w, acc[r][3]);
                }
            }
        }
    }

    float bias[4];
    #pragma unroll
    for (int o = 0; o < 4; ++o) bias[o] = b1[og * 4 + o];
    // oc = og*4+o  ->  pair planes p = og*2 + {0,1}
    #pragma unroll
    for (int zl = 0; zl < 8; ++zl) {
        int vox = ((z0 + zl) * 64 + y) * 64 + x;
        float2 s0 = make_float2(fmaxf(acc[zl][0] + bias[0], 0.f), fmaxf(acc[zl][1] + bias[1], 0.f));
        float2 s1 = make_float2(fmaxf(acc[zl][2] + bias[2], 0.f), fmaxf(acc[zl][3] + bias[3], 0.f));
        *reinterpret_cast<float2*>(h1p + ((size_t)(og * 2 + 0) * NVOX + vox) * 2) = s0;
        *reinterpret_cast<float2*>(h1p + ((size_t)(og * 2 + 1) * NVOX + vox) * 2) = s1;
    }
}

// ------- conv2 (64->32): Zd=8, oc=4, all-tap LDS weights, og-adjacent dispatch -------
// grid 1024 = 8 zg (XCD) x 8 og x 16 yt; og varies fastest -> data-sharers launch-adjacent.
__global__ __launch_bounds__(256, 4) void conv2_kernel(
    const float* __restrict__ h1p,    // [32][NVOX][2]
    const float* __restrict__ w2t,    // [(nb*64+ci)][32]
    const float* __restrict__ b2,
    float* __restrict__ pf)           // [vox][32] post-relu
{
    __shared__ float lw[27 * 64 * 4];  // this og's weights, all taps: 27648 B

    int tid = threadIdx.x;
    int B = blockIdx.x;
    int zg = B & 7;
    int k  = B >> 3;                   // 0..127
    int og = k & 7;                    // oc group of 4 (fastest)
    int yt = k >> 3;                   // 0..15

    for (int t = tid; t < 27 * 64 * 4; t += 256)
        lw[t] = w2t[(t >> 2) * 32 + og * 4 + (t & 3)];
    __syncthreads();                   // the only barrier

    int x  = tid & 63;
    int y  = yt * 4 + (tid >> 6);      // wave-uniform
    int z0 = zg * 8;

    float acc[8][4];
    #pragma unroll
    for (int r = 0; r < 8; ++r)
        #pragma unroll
        for (int o = 0; o < 4; ++o) acc[r][o] = 0.f;

    int zoffv[10]; float mzv[10];
    #pragma unroll
    for (int rz = 0; rz < 10; ++rz) {
        int gz = z0 - 1 + rz;
        int cz = gz < 0 ? 0 : (gz > 63 ? 63 : gz);
        zoffv[rz] = cz * 4096;
        mzv[rz] = ((unsigned)gz < 64u) ? 1.f : 0.f;
    }

    #pragma unroll 1
    for (int dydx = 0; dydx < 9; ++dydx) {
        int dy = dydx / 3 - 1;
        int dx = dydx % 3 - 1;
        int ny = y + dy;
        if ((unsigned)ny >= 64u) continue;             // wave-uniform zero-pad skip
        int nx = x + dx;
        float mx = ((unsigned)nx < 64u) ? 1.f : 0.f;
        int cx = nx < 0 ? 0 : (nx > 63 ? 63 : nx);
        int rowvox = ny * 64 + cx;

        float cm[10]; int voff[10];
        #pragma unroll
        for (int rz = 0; rz < 10; ++rz) { cm[rz] = mx * mzv[rz]; voff[rz] = zoffv[rz] + rowvox; }

        #pragma unroll 1
        for (int cq = 0; cq < 32; ++cq) {              // ci pairs
            const float* plane = h1p + (size_t)cq * (NVOX * 2);
            float2 v[10];
            #pragma unroll
            for (int rz = 0; rz < 10; ++rz) {
                float2 t2 = *reinterpret_cast<const float2*>(plane + (size_t)voff[rz] * 2);
                v[rz] = make_float2(t2.x * cm[rz], t2.y * cm[rz]);
            }
            #pragma unroll
            for (int dzi = 0; dzi < 3; ++dzi) {
                const float4* wp = reinterpret_cast<const float4*>(
                    &lw[(((dzi * 9 + dydx) * 64) + cq * 2) * 4]);
                float4 w0 = wp[0];                     // ci0 -> oc0..3
                float4 w1 = wp[1];                     // ci1 -> oc0..3
                #pragma unroll
                for (int r = 0; r < 8; ++r) {
                    float2 a = v[r + dzi];
                    acc[r][0] = fmaf(a.x, w0.x, acc[r][0]);
                    acc[r][1] = fmaf(a.x, w0.y, acc[r][1]);
                    acc[r][2] = fmaf(a.x, w0.z, acc[r][2]);
                    acc[r][3] = fmaf(a.x, w0.w, acc[r][3]);
                    acc[r][0] = fmaf(a.y, w1.x, acc[r][0]);
                    acc[r][1] = fmaf(a.y, w1.y, acc[r][1]);
                    acc[r][2] = fmaf(a.y, w1.z, acc[r][2]);
                    acc[r][3] = fmaf(a.y, w1.w, acc[r][3]);
                }
            }
        }
    }

    float bias[4];
    #pragma unroll
    for (int o = 0; o < 4; ++o) bias[o] = b2[og * 4 + o];
    #pragma unroll
    for (int zl = 0; zl < 8; ++zl) {
        int vox = ((z0 + zl) * 64 + y) * 64 + x;
        float4 s = make_float4(fmaxf(acc[zl][0] + bias[0], 0.f), fmaxf(acc[zl][1] + bias[1], 0.f),
                               fmaxf(acc[zl][2] + bias[2], 0.f), fmaxf(acc[zl][3] + bias[3], 0.f));
        *reinterpret_cast<float4*>(pf + (size_t)vox * 32 + og * 4) = s;
    }
}

// ------- epilogue: heads + argmax + argmin over seeds + mismatch scatter -------
__global__ __launch_bounds__(256) void epilogue_kernel(
    const float* __restrict__ pf,     // [vox][32] post-relu
    const float* __restrict__ points, // [N][3]
    const float* __restrict__ ann,    // [512][4]
    const float* __restrict__ sem_w, const float* __restrict__ sem_b,
    const float* __restrict__ off_w, const float* __restrict__ off_b,
    float* __restrict__ out_logits,   // [N][20]
    float* __restrict__ out_off,      // [N][3]
    int* __restrict__ iv_out,         // [N]
    int* __restrict__ bad_seed)       // [512]
{
    __shared__ float4 sseed[NSEED];
    for (int i = threadIdx.x; i < NSEED; i += 256) {
        float4 a = *reinterpret_cast<const float4*>(ann + i * 4);
        sseed[i] = make_float4(a.x, a.y, a.z, a.x*a.x + a.y*a.y + a.z*a.z);
    }
    __syncthreads();

    int vox = blockIdx.x * 256 + threadIdx.x;

    float f[32];
    #pragma unroll
    for (int q = 0; q < 8; ++q) {
        float4 v = *reinterpret_cast<const float4*>(pf + (size_t)vox * 32 + q * 4);
        f[q*4+0] = v.x; f[q*4+1] = v.y; f[q*4+2] = v.z; f[q*4+3] = v.w;
    }

    // semantic head + argmax (strict > = first occurrence)
    float best = -1e30f; int am = 0;
    #pragma unroll
    for (int cc = 0; cc < NCLS; ++cc) {
        float l = sem_b[cc];
        #pragma unroll
        for (int q = 0; q < 32; ++q) l = fmaf(f[q], sem_w[cc * 32 + q], l);
        out_logits[(size_t)vox * NCLS + cc] = l;
        if (l > best) { best = l; am = cc; }
    }

    // offset head
    float off[3];
    #pragma unroll
    for (int k3 = 0; k3 < 3; ++k3) {
        float l = off_b[k3];
        #pragma unroll
        for (int q = 0; q < 32; ++q) l = fmaf(f[q], off_w[k3 * 32 + q], l);
        out_off[(size_t)vox * 3 + k3] = l;
        off[k3] = l;
    }

    float px = points[(size_t)vox * 3 + 0] + off[0];
    float py = points[(size_t)vox * 3 + 1] + off[1];
    float pz = points[(size_t)vox * 3 + 2] + off[2];
    float pp = px * px + py * py + pz * pz;

    float bd2 = 1e30f; int bj = 0;
    #pragma unroll 4
    for (int j = 0; j < NSEED; ++j) {
        float4 s = sseed[j];                    // broadcast, conflict-free
        float dot = px * s.x + py * s.y + pz * s.z;
        float d2  = pp + s.w - 2.0f * dot;
        if (d2 < bd2) { bd2 = d2; bj = j; }     // strict < = first occurrence
    }
    float mind = sqrtf(fmaxf(bd2, 0.f));
    bool valid = mind < 1.5f;

    int slab = (int)ann[bj * 4 + 3];
    if (valid && am != slab) atomicOr(&bad_seed[bj], 1);
    iv_out[vox] = valid ? bj : -1;
}

// ---------------- finalize pseudo labels ----------------
__global__ void finalize_kernel(const int* __restrict__ iv,
                                const int* __restrict__ bad,
                                float* __restrict__ pl) {
    int t = blockIdx.x * 256 + threadIdx.x;
    if (t >= NVOX) return;
    int v = iv[t];
    float r = -1.0f;
    if (v >= 0 && bad[v] == 0) r = (float)v;
    pl[t] = r;
}

extern "C" void kernel_launch(void* const* d_in, const int* in_sizes, int n_in,
                              void* d_out, int out_size, void* d_ws, size_t ws_size,
                              hipStream_t stream) {
    const float* points   = (const float*)d_in[0];
    const float* features = (const float*)d_in[1];
    const float* ann      = (const float*)d_in[2];
    const float* w1       = (const float*)d_in[3];
    const float* b1       = (const float*)d_in[4];
    const float* w2       = (const float*)d_in[5];
    const float* b2       = (const float*)d_in[6];
    const float* sem_w    = (const float*)d_in[7];
    const float* sem_b    = (const float*)d_in[8];
    const float* off_w    = (const float*)d_in[9];
    const float* off_b    = (const float*)d_in[10];

    float* out        = (float*)d_out;
    float* out_logits = out;
    float* out_off    = out + (size_t)NVOX * NCLS;   // N*20
    float* out_pl     = out + (size_t)NVOX * 23;     // N*23

    // workspace layout (bytes, 256-aligned)
    char*  ws  = (char*)d_ws;
    float* w1t = (float*)(ws);                 //    41472 B
    float* w2t = (float*)(ws + 41472);         //   221184 B
    int*   bad = (int*)  (ws + 262656);        //     2048 B
    int*   iv  = (int*)  (ws + 264704);        //  1048576 B
    float* pf  = (float*)(ws + 1313280);       // 33554432 B
    float* h1p = (float*)(ws + 34867712);      // 67108864 B  (total ~97.3 MB)

    hipMemsetAsync(bad, 0, NSEED * sizeof(int), stream);
    transpose_all<<<257, 256, 0, stream>>>(w1, w1t, w2, w2t);
    conv1_kernel<<<2048, 256, 0, stream>>>(features, w1t, b1, h1p);
    conv2_kernel<<<1024, 256, 0, stream>>>(h1p, w2t, b2, pf);
    epilogue_kernel<<<1024, 256, 0, stream>>>(pf, points, ann,
        sem_w, sem_b, off_w, off_b, out_logits, out_off, iv, bad);
    finalize_kernel<<<1024, 256, 0, stream>>>(iv, bad, out_pl);
}